// Round 9
// baseline (78.034 us; speedup 1.0000x reference)
//
#include <hip/hip_runtime.h>
#include <hip/hip_bf16.h>

#define TPB 256
#define NEXPERT 64
#define CHUNK 256            // == TPB; chunk c == scatter block c

typedef float f32x4 __attribute__((ext_vector_type(4)));

// ---------------------------------------------------------------------------
// R9 = R8 with k_hist folded into k_scatter => single prelude dispatch.
// Each of the NB scatter blocks redundantly builds the full per-chunk
// histogram table in LDS from the whole expert array:
//   - int4 coalesced loads, addresses affine in the loop counter ->
//     independent, fully pipelined (NOT R6's ballot-synchronized chain)
//   - fire-and-forget LDS atomicAdd into cnt[e*NB + c] (no dep chain)
// Then the R8-proven exclusive scan in LDS + ballot stable rank, unchanged.
// ---------------------------------------------------------------------------
__global__ __launch_bounds__(TPB) void k_scatter(
    const int* __restrict__ expert, const int* __restrict__ rowi,
    int NK, int NB,
    float* __restrict__ out_row, float* __restrict__ out_expert,
    int* __restrict__ dst_of_r) {
    extern __shared__ int lds[];             // [M] counts | [TPB] scan temp
    __shared__ int h[TPB / 64][NEXPERT + 1];
    const int M = NEXPERT * NB;
    int* cnt = lds;
    int* s = lds + M;
    const int b = blockIdx.x;
    const int tid = threadIdx.x;
    const int w = tid >> 6;
    const int lane = tid & 63;

    for (int j = tid; j < M; j += TPB) cnt[j] = 0;
    for (int idx = tid; idx < (TPB / 64) * (NEXPERT + 1); idx += TPB)
        (&h[0][0])[idx] = 0;
    __syncthreads();

    // ---- histogram of the WHOLE array, int4-vectorized ----
    const int NK4 = NK >> 2;                 // int4 count
    const int4* __restrict__ e4 = (const int4*)expert;
    for (int j4 = tid; j4 < NK4; j4 += TPB) {
        const int4 v = e4[j4];
        const int base_idx = j4 << 2;
        atomicAdd(&cnt[v.x * NB + ((base_idx + 0) >> 8)], 1);
        atomicAdd(&cnt[v.y * NB + ((base_idx + 1) >> 8)], 1);
        atomicAdd(&cnt[v.z * NB + ((base_idx + 2) >> 8)], 1);
        atomicAdd(&cnt[v.w * NB + ((base_idx + 3) >> 8)], 1);
    }
    for (int idx = (NK4 << 2) + tid; idx < NK; idx += TPB)   // tail (none here)
        atomicAdd(&cnt[expert[idx] * NB + (idx >> 8)], 1);
    __syncthreads();

    // ---- exclusive scan of cnt[0..M) in LDS (R8-proven) ----
    const int ipt = (M + TPB - 1) / TPB;     // 16 for the 8192x4096 shape
    const int base_i = tid * ipt;
    int sum = 0;
    for (int j = 0; j < ipt; ++j) sum += (base_i + j < M) ? cnt[base_i + j] : 0;
    s[tid] = sum;
    __syncthreads();
    for (int off = 1; off < TPB; off <<= 1) {
        const int xv = (tid >= off) ? s[tid - off] : 0;
        __syncthreads();
        s[tid] += xv;
        __syncthreads();
    }
    int run = (tid == 0) ? 0 : s[tid - 1];
    for (int j = 0; j < ipt; ++j) {
        if (base_i + j < M) {
            const int c = cnt[base_i + j];
            cnt[base_i + j] = run;
            run += c;
        }
    }
    __syncthreads();

    // ---- ballot-based stable rank (byte-identical to R2/R8) ----
    const int i = b * TPB + tid;
    const bool valid = (i < NK);
    const int e = valid ? expert[i] : NEXPERT;   // sentinel for inactive lanes

    unsigned long long mask = ~0ull;
#pragma unroll
    for (int bit = 0; bit < 7; ++bit) {
        const unsigned long long bv = __ballot((e >> bit) & 1);
        mask &= ((e >> bit) & 1) ? bv : ~bv;
    }
    const int rank_w = __popcll(mask & ((1ull << lane) - 1ull));
    const int cnt_w  = __popcll(mask);
    if (rank_w == 0) h[w][e] = cnt_w;   // lowest lane of each expert group
    __syncthreads();

    if (valid) {
        int rank = rank_w;
        for (int w2 = 0; w2 < w; ++w2) rank += h[w2][e];
        const int dst = cnt[e * NB + b] + rank;
        const int r = rowi[i];
        out_expert[dst] = (float)e;
        out_row[r] = (float)dst;
        dst_of_r[r] = dst;
    }
}

// K2: token-driven gather (byte-identical to R2/R8's validated winner).
template <int K>
__global__ void k_gatherT(const float* __restrict__ x,
                          const int* __restrict__ dst_of_r,
                          float* __restrict__ out_x, int H, int N) {
    const int t = blockIdx.x;
    const f32x4* __restrict__ src = (const f32x4*)(x + (size_t)t * (size_t)H);
    size_t ob[K];
#pragma unroll
    for (int kk = 0; kk < K; ++kk)
        ob[kk] = (size_t)dst_of_r[t + kk * N] * (size_t)H;
    const int n4 = H >> 2;
    for (int j = threadIdx.x; j < n4; j += blockDim.x) {
        const f32x4 v = src[j];
#pragma unroll
        for (int kk = 0; kk < K; ++kk)
            __builtin_nontemporal_store(v, (f32x4*)(out_x + ob[kk]) + j);
    }
}

// Generic-K fallback (only used for K > 4)
__global__ void k_gather_gen(const float* __restrict__ x,
                             const int* __restrict__ dst_of_r,
                             float* __restrict__ out_x, int H, int N, int K) {
    const int t = blockIdx.x;
    const f32x4* __restrict__ src = (const f32x4*)(x + (size_t)t * (size_t)H);
    const int n4 = H >> 2;
    for (int kk = 0; kk < K; ++kk) {
        const size_t ob = (size_t)dst_of_r[t + kk * N] * (size_t)H;
        for (int j = threadIdx.x; j < n4; j += blockDim.x)
            __builtin_nontemporal_store(src[j], (f32x4*)(out_x + ob) + j);
    }
}

extern "C" void kernel_launch(void* const* d_in, const int* in_sizes, int n_in,
                              void* d_out, int out_size, void* d_ws, size_t ws_size,
                              hipStream_t stream) {
    const float* x    = (const float*)d_in[0];  // [N, H] fp32
    const int*   rowi = (const int*)d_in[1];    // [N, K] int32 (arange)
    const int*   expi = (const int*)d_in[2];    // [N, K] int32

    const int NK = in_sizes[1];                    // N*K = 16384
    const int H  = (out_size - 2 * NK) / NK;       // 4096
    const int N  = in_sizes[0] / H;                // 8192
    const int K  = NK / N;                         // 2
    const int NB = (NK + TPB - 1) / TPB;           // 64 chunks

    // Output layout (all float32): [NK*H] expanded_x | [NK] row_idx | [NK] expert_idx
    float* out_x      = (float*)d_out;
    float* out_row    = out_x + (size_t)NK * (size_t)H;
    float* out_expert = out_row + NK;

    int* dst_of_r = (int*)d_ws;

    const int M = NEXPERT * NB;
    const size_t lds_bytes = (size_t)(M + TPB) * sizeof(int);

    k_scatter<<<NB, TPB, lds_bytes, stream>>>(expi, rowi, NK, NB,
                                              out_row, out_expert, dst_of_r);

    switch (K) {
        case 1: k_gatherT<1><<<N, TPB, 0, stream>>>(x, dst_of_r, out_x, H, N); break;
        case 2: k_gatherT<2><<<N, TPB, 0, stream>>>(x, dst_of_r, out_x, H, N); break;
        case 3: k_gatherT<3><<<N, TPB, 0, stream>>>(x, dst_of_r, out_x, H, N); break;
        case 4: k_gatherT<4><<<N, TPB, 0, stream>>>(x, dst_of_r, out_x, H, N); break;
        default: k_gather_gen<<<N, TPB, 0, stream>>>(x, dst_of_r, out_x, H, N, K); break;
    }
}